// Round 6
// baseline (387.571 us; speedup 1.0000x reference)
//
#include <hip/hip_runtime.h>
#include <hip/hip_bf16.h>

typedef unsigned short ushort_t;
typedef __attribute__((ext_vector_type(8))) short short8;
typedef __attribute__((ext_vector_type(4))) float floatx4;

#define LOG2E 1.4426950408889634f

__device__ __forceinline__ unsigned short f2bf(float f) {
    unsigned u = __float_as_uint(f);
    u += 0x7FFF + ((u >> 16) & 1);   // RNE
    return (unsigned short)(u >> 16);
}

__device__ __forceinline__ void async_ld16(const void* gptr, void* lptr) {
    typedef const __attribute__((address_space(1))) unsigned int TG;
    typedef __attribute__((address_space(3))) unsigned int TL;
    __builtin_amdgcn_global_load_lds((TG*)(unsigned long long)gptr,
                                     (TL*)(unsigned)(unsigned long long)lptr,
                                     16, 0, 0);
}

// ---------------- fused prep: x->bf16 | w_qkv transpose | w_proj transpose ----------------
__global__ __launch_bounds__(256) void prep_kernel(const float* __restrict__ x,
                                                   const float* __restrict__ wqkv,
                                                   const float* __restrict__ wproj,
                                                   ushort_t* __restrict__ xb,
                                                   ushort_t* __restrict__ wqkvT,
                                                   ushort_t* __restrict__ wprojT) {
    __shared__ float t[32][33];
    int bx = blockIdx.x;
    if (bx < 8192) {
        int i = bx * 256 + threadIdx.x;
        float4 v = ((const float4*)x)[i];
        unsigned long long r = (unsigned long long)f2bf(v.x)
                             | ((unsigned long long)f2bf(v.y) << 16)
                             | ((unsigned long long)f2bf(v.z) << 32)
                             | ((unsigned long long)f2bf(v.w) << 48);
        ((unsigned long long*)xb)[i] = r;
        return;
    }
    const float* in; ushort_t* out; int R, C, bidx;
    if (bx < 8192 + 3072) { in = wqkv; out = wqkvT; R = 1024; C = 3072; bidx = bx - 8192; }
    else                  { in = wproj; out = wprojT; R = 1024; C = 1024; bidx = bx - 11264; }
    int nbc = C >> 5;
    int bc = bidx % nbc, br = bidx / nbc;
    int tx = threadIdx.x & 31, ty = threadIdx.x >> 5;   // 32 x 8
    int r0 = br << 5, c0 = bc << 5;
#pragma unroll
    for (int j = 0; j < 4; ++j)
        t[ty + j * 8][tx] = in[(size_t)(r0 + ty + j * 8) * C + c0 + tx];
    __syncthreads();
#pragma unroll
    for (int j = 0; j < 4; ++j)
        out[(size_t)(c0 + ty + j * 8) * R + r0 + tx] = f2bf(t[tx][ty + j * 8]);
}

// ---------------- QKV GEMM: [8192,1024]@[1024,3072]^T + bias -> split Q/K/Vt ----------------
// Q,K: [bh][s][64] bf16 ; Vt: [bh][64][2048] bf16
// Q (incl. bias) is pre-scaled by 0.125*log2(e) so attn can use exp2 directly.
__global__ __launch_bounds__(256) void gemm_qkv_kernel(const ushort_t* __restrict__ A,
                                                       const ushort_t* __restrict__ Bt,
                                                       const float* __restrict__ bias,
                                                       ushort_t* __restrict__ qbuf,
                                                       ushort_t* __restrict__ kbuf,
                                                       ushort_t* __restrict__ vtbuf) {
    const int K = 1024, nbn = 24;
    __shared__ __align__(16) ushort_t As[128 * 32];
    __shared__ __align__(16) ushort_t Bs[128 * 32];
    int bm = blockIdx.x / nbn, bn = blockIdx.x % nbn;
    int m0 = bm << 7, n0 = bn << 7;
    int tid = threadIdx.x;
    int wave = tid >> 6, lane = tid & 63;
    int c = lane & 15, g = lane >> 4;
    int m_off = (wave & 1) << 6, n_off = (wave >> 1) << 6;
    int ldrow = lane >> 2;
    int ldk   = (lane & 3) << 3;

    floatx4 acc[4][4];
#pragma unroll
    for (int mi = 0; mi < 4; ++mi)
#pragma unroll
        for (int ni = 0; ni < 4; ++ni) {
            floatx4 z = {0.f, 0.f, 0.f, 0.f};
            acc[mi][ni] = z;
        }

    for (int kk = 0; kk < K; kk += 32) {
        __syncthreads();
#pragma unroll
        for (int j = 0; j < 2; ++j) {
            int chunk = wave * 2 + j;
            async_ld16(A  + (size_t)(m0 + chunk * 16 + ldrow) * K + kk + ldk, &As[chunk * 512]);
            async_ld16(Bt + (size_t)(n0 + chunk * 16 + ldrow) * K + kk + ldk, &Bs[chunk * 512]);
        }
        __syncthreads();
        short8 bf[4];
#pragma unroll
        for (int ni = 0; ni < 4; ++ni)
            bf[ni] = *(const short8*)&Bs[(n_off + ni * 16 + c) * 32 + g * 8];
#pragma unroll
        for (int mi = 0; mi < 4; ++mi) {
            short8 af = *(const short8*)&As[(m_off + mi * 16 + c) * 32 + g * 8];
#pragma unroll
            for (int ni = 0; ni < 4; ++ni)
                acc[mi][ni] = __builtin_amdgcn_mfma_f32_16x16x32_bf16(af, bf[ni], acc[mi][ni], 0, 0, 0);
        }
    }

    int sec = n0 >> 10;               // 0=Q 1=K 2=V (block-uniform; 1024%128==0)
    float scl = (sec == 0) ? (0.125f * LOG2E) : 1.0f;
    float bv[4]; int hh[4], dd[4];
#pragma unroll
    for (int ni = 0; ni < 4; ++ni) {
        int coln = n0 + n_off + ni * 16 + c;
        bv[ni] = bias[coln];
        int coll = coln & 1023;
        hh[ni] = coll >> 6; dd[ni] = coll & 63;
    }
#pragma unroll
    for (int mi = 0; mi < 4; ++mi) {
        int rowb = m0 + m_off + mi * 16 + g * 4;     // +r
        int bb = rowb >> 11, sbase = rowb & 2047;
#pragma unroll
        for (int ni = 0; ni < 4; ++ni) {
            size_t bhn = (size_t)(bb * 16 + hh[ni]);
            if (sec == 2) {
                unsigned long long pk = 0;
#pragma unroll
                for (int r = 0; r < 4; ++r)
                    pk |= (unsigned long long)f2bf(acc[mi][ni][r] + bv[ni]) << (16 * r);
                *(unsigned long long*)(vtbuf + bhn * 131072 + (size_t)dd[ni] * 2048 + sbase) = pk;
            } else {
                ushort_t* dst = (sec == 0 ? qbuf : kbuf) + (bhn * 2048 + sbase) * 64 + dd[ni];
#pragma unroll
                for (int r = 0; r < 4; ++r)
                    dst[r * 64] = f2bf((acc[mi][ni][r] + bv[ni]) * scl);
            }
        }
    }
}

// ---------------- flash attention: 1 block = (b,h) x 128 q-rows, 64-kp tiles ----------------
// 26.1 KB LDS -> 5 blocks/CU (launch_bounds(256,5)): occupancy attack on the
// latency-bound profile (R5: nothing saturated, 3 blocks/CU). Transposed
// softmax, no online max, shared kf across strips, LPT dispatch, post-barrier
// register prefetch.
__global__ __launch_bounds__(256, 5) void attn_kernel(const ushort_t* __restrict__ qb_,
                                                      const ushort_t* __restrict__ kb_,
                                                      const ushort_t* __restrict__ vtb_,
                                                      ushort_t* __restrict__ aout) {
    __shared__ __align__(16) ushort_t Ks[64 * 68];       // [kp][d] stride 68
    __shared__ __align__(16) ushort_t Vs[64 * 68];       // [d][kp] stride 68
    __shared__ __align__(16) ushort_t Ps[4][16 * 68];    // per-wave P[q][kp]
    int bx = blockIdx.x;
    int qb = 15 - (bx >> 6);          // LPT: all qb=15 blocks dispatch first
    int bhix = bx & 63;
    int b = bhix >> 4, h = bhix & 15;
    int q0 = qb << 7;
    int tid = threadIdx.x, wave = tid >> 6, lane = tid & 63;
    int c = lane & 15, g = lane >> 4;
    size_t bh = (size_t)(b * 16 + h);

    const ushort_t* Qp = qb_ + (bh * 2048 + q0) * 64;
    const ushort_t* Kp = kb_ + bh * 131072;
    const ushort_t* Vp = vtb_ + bh * 131072;

    short8 qf[2][2];
#pragma unroll
    for (int ss = 0; ss < 2; ++ss) {
        int qr = (wave * 2 + ss) * 16 + c;
        qf[ss][0] = *(const short8*)(Qp + qr * 64 + g * 8);
        qf[ss][1] = *(const short8*)(Qp + qr * 64 + 32 + g * 8);
    }

    float l_part[2] = {0.f, 0.f};
    floatx4 o_acc[2][4];
#pragma unroll
    for (int ss = 0; ss < 2; ++ss)
#pragma unroll
        for (int nt = 0; nt < 4; ++nt) { floatx4 z = {0.f,0.f,0.f,0.f}; o_acc[ss][nt] = z; }

    // prefetch tile 0 into regs (64 kp x 64 d = 8 KB each for K and V)
    short8 kreg[2], vreg[2];
#pragma unroll
    for (int it = 0; it < 2; ++it) {
        int idx = it * 256 + tid;
        kreg[it] = *(const short8*)(Kp + idx * 8);
        vreg[it] = *(const short8*)(Vp + (idx >> 3) * 2048 + (idx & 7) * 8);
    }

    int qg0 = q0 + wave * 32 + c;      // strip-0 q row; strip-1 = +16
    int kt_last = 2 * qb + 1;
    for (int kt = 0; kt <= kt_last; ++kt) {
        int kt0 = kt << 6;
        __syncthreads();
#pragma unroll
        for (int it = 0; it < 2; ++it) {
            int idx = it * 256 + tid;
            *(short8*)&Ks[(idx >> 3) * 68 + (idx & 7) * 8] = kreg[it];
            *(short8*)&Vs[(idx >> 3) * 68 + (idx & 7) * 8] = vreg[it];
        }
        __syncthreads();
        // prefetch next tile AFTER the barrier (in flight through compute)
        if (kt < kt_last) {
            int s0 = (kt + 1) << 6;
#pragma unroll
            for (int it = 0; it < 2; ++it) {
                int idx = it * 256 + tid;
                kreg[it] = *(const short8*)(Kp + s0 * 64 + idx * 8);
                vreg[it] = *(const short8*)(Vp + (idx >> 3) * 2048 + s0 + (idx & 7) * 8);
            }
        }
        bool diag = (kt >= 2 * qb);    // last two 64-kp tiles overlap the diagonal

        // ---- QK both strips per kf read; strip0 P -> LDS, strip1 P -> regs
        unsigned pd[4][2];
        float lp0 = 0.f, lp1 = 0.f;
#pragma unroll
        for (int nt = 0; nt < 4; ++nt) {
            short8 kf0 = *(const short8*)&Ks[(nt * 16 + c) * 68 + g * 8];
            short8 kf1 = *(const short8*)&Ks[(nt * 16 + c) * 68 + 32 + g * 8];
            floatx4 z0 = {0.f, 0.f, 0.f, 0.f};
            z0 = __builtin_amdgcn_mfma_f32_16x16x32_bf16(kf0, qf[0][0], z0, 0, 0, 0);
            z0 = __builtin_amdgcn_mfma_f32_16x16x32_bf16(kf1, qf[0][1], z0, 0, 0, 0);
            floatx4 z1 = {0.f, 0.f, 0.f, 0.f};
            z1 = __builtin_amdgcn_mfma_f32_16x16x32_bf16(kf0, qf[1][0], z1, 0, 0, 0);
            z1 = __builtin_amdgcn_mfma_f32_16x16x32_bf16(kf1, qf[1][1], z1, 0, 0, 0);

            int kpb = kt0 + nt * 16 + g * 4;
            float p0[4], p1[4];
#pragma unroll
            for (int r = 0; r < 4; ++r) {
                float s0v = z0[r], s1v = z1[r];
                if (diag) {
                    int kp = kpb + r;
                    s0v = (kp > qg0)      ? -1e30f : s0v;
                    s1v = (kp > qg0 + 16) ? -1e30f : s1v;
                }
                p0[r] = exp2f(s0v); lp0 += p0[r];
                p1[r] = exp2f(s1v); lp1 += p1[r];
            }
            union { unsigned long long u; __hip_bfloat162 h[2]; unsigned w[2]; } pk;
            pk.h[0] = __float22bfloat162_rn(make_float2(p0[0], p0[1]));
            pk.h[1] = __float22bfloat162_rn(make_float2(p0[2], p0[3]));
            *(unsigned long long*)&Ps[wave][c * 68 + nt * 16 + g * 4] = pk.u;
            pk.h[0] = __float22bfloat162_rn(make_float2(p1[0], p1[1]));
            pk.h[1] = __float22bfloat162_rn(make_float2(p1[2], p1[3]));
            pd[nt][0] = pk.w[0]; pd[nt][1] = pk.w[1];
        }
        l_part[0] += lp0;
        l_part[1] += lp1;

        // ---- PV strip 0 (P from LDS)
#pragma unroll
        for (int ks = 0; ks < 2; ++ks) {
            short8 pf = *(const short8*)&Ps[wave][c * 68 + ks * 32 + g * 8];
#pragma unroll
            for (int nt = 0; nt < 4; ++nt) {
                short8 vf = *(const short8*)&Vs[(nt * 16 + c) * 68 + ks * 32 + g * 8];
                o_acc[0][nt] = __builtin_amdgcn_mfma_f32_16x16x32_bf16(pf, vf, o_acc[0][nt], 0, 0, 0);
            }
        }
        // ---- strip-1 P regs -> LDS (per-wave slot; lgkm-ordered within wave)
#pragma unroll
        for (int nt = 0; nt < 4; ++nt) {
            union { unsigned long long u; unsigned w[2]; } pk;
            pk.w[0] = pd[nt][0]; pk.w[1] = pd[nt][1];
            *(unsigned long long*)&Ps[wave][c * 68 + nt * 16 + g * 4] = pk.u;
        }
        // ---- PV strip 1
#pragma unroll
        for (int ks = 0; ks < 2; ++ks) {
            short8 pf = *(const short8*)&Ps[wave][c * 68 + ks * 32 + g * 8];
#pragma unroll
            for (int nt = 0; nt < 4; ++nt) {
                short8 vf = *(const short8*)&Vs[(nt * 16 + c) * 68 + ks * 32 + g * 8];
                o_acc[1][nt] = __builtin_amdgcn_mfma_f32_16x16x32_bf16(pf, vf, o_acc[1][nt], 0, 0, 0);
            }
        }
    }

    // epilogue: reduce l across g-groups, broadcast, O/l -> a[b][s][h*64+d]
#pragma unroll
    for (int ss = 0; ss < 2; ++ss) {
        float l = l_part[ss];
        l += __shfl_xor(l, 16);
        l += __shfl_xor(l, 32);
        float linv = 1.0f / l;
        float inv[4];
#pragma unroll
        for (int r = 0; r < 4; ++r)
            inv[r] = __shfl(linv, g * 4 + r);
#pragma unroll
        for (int nt = 0; nt < 4; ++nt)
#pragma unroll
            for (int r = 0; r < 4; ++r) {
                int q = q0 + (wave * 2 + ss) * 16 + g * 4 + r;
                aout[(size_t)(b * 2048 + q) * 1024 + h * 64 + nt * 16 + c] =
                    f2bf(o_acc[ss][nt][r] * inv[r]);
            }
    }
}

// ---------------- proj GEMM: [8192,1024]@[1024,1024]^T + bias -> fp32 ----------------
__global__ __launch_bounds__(256) void gemm_proj_kernel(const ushort_t* __restrict__ A,
                                                        const ushort_t* __restrict__ Bt,
                                                        const float* __restrict__ bias,
                                                        float* __restrict__ Cout) {
    const int K = 1024, N = 1024, nbn = 8;
    __shared__ __align__(16) ushort_t As[128 * 32];
    __shared__ __align__(16) ushort_t Bs[128 * 32];
    int bm = blockIdx.x / nbn, bn = blockIdx.x % nbn;
    int m0 = bm << 7, n0 = bn << 7;
    int tid = threadIdx.x;
    int wave = tid >> 6, lane = tid & 63;
    int c = lane & 15, g = lane >> 4;
    int m_off = (wave & 1) << 6, n_off = (wave >> 1) << 6;
    int ldrow = lane >> 2;
    int ldk   = (lane & 3) << 3;

    floatx4 acc[4][4];
#pragma unroll
    for (int mi = 0; mi < 4; ++mi)
#pragma unroll
        for (int ni = 0; ni < 4; ++ni) {
            floatx4 z = {0.f, 0.f, 0.f, 0.f};
            acc[mi][ni] = z;
        }

    for (int kk = 0; kk < K; kk += 32) {
        __syncthreads();
#pragma unroll
        for (int j = 0; j < 2; ++j) {
            int chunk = wave * 2 + j;
            async_ld16(A  + (size_t)(m0 + chunk * 16 + ldrow) * K + kk + ldk, &As[chunk * 512]);
            async_ld16(Bt + (size_t)(n0 + chunk * 16 + ldrow) * K + kk + ldk, &Bs[chunk * 512]);
        }
        __syncthreads();
        short8 bf[4];
#pragma unroll
        for (int ni = 0; ni < 4; ++ni)
            bf[ni] = *(const short8*)&Bs[(n_off + ni * 16 + c) * 32 + g * 8];
#pragma unroll
        for (int mi = 0; mi < 4; ++mi) {
            short8 af = *(const short8*)&As[(m_off + mi * 16 + c) * 32 + g * 8];
#pragma unroll
            for (int ni = 0; ni < 4; ++ni)
                acc[mi][ni] = __builtin_amdgcn_mfma_f32_16x16x32_bf16(af, bf[ni], acc[mi][ni], 0, 0, 0);
        }
    }

    float bv[4];
#pragma unroll
    for (int ni = 0; ni < 4; ++ni) bv[ni] = bias[n0 + n_off + ni * 16 + c];
#pragma unroll
    for (int mi = 0; mi < 4; ++mi)
#pragma unroll
        for (int ni = 0; ni < 4; ++ni)
#pragma unroll
            for (int r = 0; r < 4; ++r) {
                int row = m0 + m_off + mi * 16 + g * 4 + r;
                int col = n0 + n_off + ni * 16 + c;
                Cout[(size_t)row * N + col] = acc[mi][ni][r] + bv[ni];
            }
}

extern "C" void kernel_launch(void* const* d_in, const int* in_sizes, int n_in,
                              void* d_out, int out_size, void* d_ws, size_t ws_size,
                              hipStream_t stream) {
    const float* x        = (const float*)d_in[0];
    const float* c_attn_w = (const float*)d_in[1];
    const float* c_attn_b = (const float*)d_in[2];
    const float* c_proj_w = (const float*)d_in[3];
    const float* c_proj_b = (const float*)d_in[4];
    float* out = (float*)d_out;

    char* ws = (char*)d_ws;
    ushort_t* xb     = (ushort_t*)(ws);              // 16 MB; reused as attn output 'a'
    ushort_t* wqkvT  = (ushort_t*)(ws + 16777216);   // 6 MB
    ushort_t* wprojT = (ushort_t*)(ws + 23068672);   // 2 MB
    ushort_t* qbuf   = (ushort_t*)(ws + 25165824);   // 16 MB  [bh][s][64]  (pre-scaled)
    ushort_t* kbuf   = (ushort_t*)(ws + 41943040);   // 16 MB  [bh][s][64]
    ushort_t* vtbuf  = (ushort_t*)(ws + 58720256);   // 16 MB  [bh][64][2048]

    prep_kernel<<<12288, 256, 0, stream>>>(x, c_attn_w, c_proj_w, xb, wqkvT, wprojT);
    gemm_qkv_kernel<<<64 * 24, 256, 0, stream>>>(xb, wqkvT, c_attn_b, qbuf, kbuf, vtbuf);
    attn_kernel<<<1024, 256, 0, stream>>>(qbuf, kbuf, vtbuf, xb);
    gemm_proj_kernel<<<64 * 8, 256, 0, stream>>>(xb, wprojT, c_proj_b, out);
}

// Round 7
// 308.270 us; speedup vs baseline: 1.2572x; 1.2572x over previous
//
#include <hip/hip_runtime.h>
#include <hip/hip_bf16.h>

typedef unsigned short ushort_t;
typedef __attribute__((ext_vector_type(8))) short short8;
typedef __attribute__((ext_vector_type(4))) float floatx4;

#define LOG2E 1.4426950408889634f

__device__ __forceinline__ unsigned short f2bf(float f) {
    unsigned u = __float_as_uint(f);
    u += 0x7FFF + ((u >> 16) & 1);   // RNE
    return (unsigned short)(u >> 16);
}

__device__ __forceinline__ void async_ld16(const void* gptr, void* lptr) {
    typedef const __attribute__((address_space(1))) unsigned int TG;
    typedef __attribute__((address_space(3))) unsigned int TL;
    __builtin_amdgcn_global_load_lds((TG*)(unsigned long long)gptr,
                                     (TL*)(unsigned)(unsigned long long)lptr,
                                     16, 0, 0);
}

// ---------------- fused prep: x->bf16 | w_qkv transpose | w_proj transpose ----------------
__global__ __launch_bounds__(256) void prep_kernel(const float* __restrict__ x,
                                                   const float* __restrict__ wqkv,
                                                   const float* __restrict__ wproj,
                                                   ushort_t* __restrict__ xb,
                                                   ushort_t* __restrict__ wqkvT,
                                                   ushort_t* __restrict__ wprojT) {
    __shared__ float t[32][33];
    int bx = blockIdx.x;
    if (bx < 8192) {
        int i = bx * 256 + threadIdx.x;
        float4 v = ((const float4*)x)[i];
        unsigned long long r = (unsigned long long)f2bf(v.x)
                             | ((unsigned long long)f2bf(v.y) << 16)
                             | ((unsigned long long)f2bf(v.z) << 32)
                             | ((unsigned long long)f2bf(v.w) << 48);
        ((unsigned long long*)xb)[i] = r;
        return;
    }
    const float* in; ushort_t* out; int R, C, bidx;
    if (bx < 8192 + 3072) { in = wqkv; out = wqkvT; R = 1024; C = 3072; bidx = bx - 8192; }
    else                  { in = wproj; out = wprojT; R = 1024; C = 1024; bidx = bx - 11264; }
    int nbc = C >> 5;
    int bc = bidx % nbc, br = bidx / nbc;
    int tx = threadIdx.x & 31, ty = threadIdx.x >> 5;   // 32 x 8
    int r0 = br << 5, c0 = bc << 5;
#pragma unroll
    for (int j = 0; j < 4; ++j)
        t[ty + j * 8][tx] = in[(size_t)(r0 + ty + j * 8) * C + c0 + tx];
    __syncthreads();
#pragma unroll
    for (int j = 0; j < 4; ++j)
        out[(size_t)(c0 + ty + j * 8) * R + r0 + tx] = f2bf(t[tx][ty + j * 8]);
}

// ---------------- QKV GEMM: [8192,1024]@[1024,3072]^T + bias -> split Q/K/Vt ----------------
// Q,K: [bh][s][64] bf16 ; Vt: [bh][64][2048] bf16
// Q (incl. bias) is pre-scaled by 0.125*log2(e) so attn can use exp2 directly.
__global__ __launch_bounds__(256) void gemm_qkv_kernel(const ushort_t* __restrict__ A,
                                                       const ushort_t* __restrict__ Bt,
                                                       const float* __restrict__ bias,
                                                       ushort_t* __restrict__ qbuf,
                                                       ushort_t* __restrict__ kbuf,
                                                       ushort_t* __restrict__ vtbuf) {
    const int K = 1024, nbn = 24;
    __shared__ __align__(16) ushort_t As[128 * 32];
    __shared__ __align__(16) ushort_t Bs[128 * 32];
    int bm = blockIdx.x / nbn, bn = blockIdx.x % nbn;
    int m0 = bm << 7, n0 = bn << 7;
    int tid = threadIdx.x;
    int wave = tid >> 6, lane = tid & 63;
    int c = lane & 15, g = lane >> 4;
    int m_off = (wave & 1) << 6, n_off = (wave >> 1) << 6;
    int ldrow = lane >> 2;
    int ldk   = (lane & 3) << 3;

    floatx4 acc[4][4];
#pragma unroll
    for (int mi = 0; mi < 4; ++mi)
#pragma unroll
        for (int ni = 0; ni < 4; ++ni) {
            floatx4 z = {0.f, 0.f, 0.f, 0.f};
            acc[mi][ni] = z;
        }

    for (int kk = 0; kk < K; kk += 32) {
        __syncthreads();
#pragma unroll
        for (int j = 0; j < 2; ++j) {
            int chunk = wave * 2 + j;
            async_ld16(A  + (size_t)(m0 + chunk * 16 + ldrow) * K + kk + ldk, &As[chunk * 512]);
            async_ld16(Bt + (size_t)(n0 + chunk * 16 + ldrow) * K + kk + ldk, &Bs[chunk * 512]);
        }
        __syncthreads();
        short8 bf[4];
#pragma unroll
        for (int ni = 0; ni < 4; ++ni)
            bf[ni] = *(const short8*)&Bs[(n_off + ni * 16 + c) * 32 + g * 8];
#pragma unroll
        for (int mi = 0; mi < 4; ++mi) {
            short8 af = *(const short8*)&As[(m_off + mi * 16 + c) * 32 + g * 8];
#pragma unroll
            for (int ni = 0; ni < 4; ++ni)
                acc[mi][ni] = __builtin_amdgcn_mfma_f32_16x16x32_bf16(af, bf[ni], acc[mi][ni], 0, 0, 0);
        }
    }

    int sec = n0 >> 10;               // 0=Q 1=K 2=V (block-uniform; 1024%128==0)
    float scl = (sec == 0) ? (0.125f * LOG2E) : 1.0f;
    float bv[4]; int hh[4], dd[4];
#pragma unroll
    for (int ni = 0; ni < 4; ++ni) {
        int coln = n0 + n_off + ni * 16 + c;
        bv[ni] = bias[coln];
        int coll = coln & 1023;
        hh[ni] = coll >> 6; dd[ni] = coll & 63;
    }
#pragma unroll
    for (int mi = 0; mi < 4; ++mi) {
        int rowb = m0 + m_off + mi * 16 + g * 4;     // +r
        int bb = rowb >> 11, sbase = rowb & 2047;
#pragma unroll
        for (int ni = 0; ni < 4; ++ni) {
            size_t bhn = (size_t)(bb * 16 + hh[ni]);
            if (sec == 2) {
                unsigned long long pk = 0;
#pragma unroll
                for (int r = 0; r < 4; ++r)
                    pk |= (unsigned long long)f2bf(acc[mi][ni][r] + bv[ni]) << (16 * r);
                *(unsigned long long*)(vtbuf + bhn * 131072 + (size_t)dd[ni] * 2048 + sbase) = pk;
            } else {
                ushort_t* dst = (sec == 0 ? qbuf : kbuf) + (bhn * 2048 + sbase) * 64 + dd[ni];
#pragma unroll
                for (int r = 0; r < 4; ++r)
                    dst[r * 64] = f2bf((acc[mi][ni][r] + bv[ni]) * scl);
            }
        }
    }
}

// ---------------- flash attention: 1 block = (b,h) x 128 q-rows, 64-kp tiles ----------------
// 26.1 KB LDS; launch_bounds(256,4) -> 128-VGPR budget (R6's (256,5) forced
// spills: VGPR 48, 314 MB scratch writes). 4 blocks/CU, conflict-free
// stride-68 LDS. Transposed softmax, no online max, shared kf across strips,
// LPT dispatch, post-barrier register prefetch.
__global__ __launch_bounds__(256, 4) void attn_kernel(const ushort_t* __restrict__ qb_,
                                                      const ushort_t* __restrict__ kb_,
                                                      const ushort_t* __restrict__ vtb_,
                                                      ushort_t* __restrict__ aout) {
    __shared__ __align__(16) ushort_t Ks[64 * 68];       // [kp][d] stride 68
    __shared__ __align__(16) ushort_t Vs[64 * 68];       // [d][kp] stride 68
    __shared__ __align__(16) ushort_t Ps[4][16 * 68];    // per-wave P[q][kp]
    int bx = blockIdx.x;
    int qb = 15 - (bx >> 6);          // LPT: all qb=15 blocks dispatch first
    int bhix = bx & 63;
    int b = bhix >> 4, h = bhix & 15;
    int q0 = qb << 7;
    int tid = threadIdx.x, wave = tid >> 6, lane = tid & 63;
    int c = lane & 15, g = lane >> 4;
    size_t bh = (size_t)(b * 16 + h);

    const ushort_t* Qp = qb_ + (bh * 2048 + q0) * 64;
    const ushort_t* Kp = kb_ + bh * 131072;
    const ushort_t* Vp = vtb_ + bh * 131072;

    short8 qf[2][2];
#pragma unroll
    for (int ss = 0; ss < 2; ++ss) {
        int qr = (wave * 2 + ss) * 16 + c;
        qf[ss][0] = *(const short8*)(Qp + qr * 64 + g * 8);
        qf[ss][1] = *(const short8*)(Qp + qr * 64 + 32 + g * 8);
    }

    float l_part[2] = {0.f, 0.f};
    floatx4 o_acc[2][4];
#pragma unroll
    for (int ss = 0; ss < 2; ++ss)
#pragma unroll
        for (int nt = 0; nt < 4; ++nt) { floatx4 z = {0.f,0.f,0.f,0.f}; o_acc[ss][nt] = z; }

    // prefetch tile 0 into regs (64 kp x 64 d = 8 KB each for K and V)
    short8 kreg[2], vreg[2];
#pragma unroll
    for (int it = 0; it < 2; ++it) {
        int idx = it * 256 + tid;
        kreg[it] = *(const short8*)(Kp + idx * 8);
        vreg[it] = *(const short8*)(Vp + (idx >> 3) * 2048 + (idx & 7) * 8);
    }

    int qg0 = q0 + wave * 32 + c;      // strip-0 q row; strip-1 = +16
    int kt_last = 2 * qb + 1;
    for (int kt = 0; kt <= kt_last; ++kt) {
        int kt0 = kt << 6;
        __syncthreads();
#pragma unroll
        for (int it = 0; it < 2; ++it) {
            int idx = it * 256 + tid;
            *(short8*)&Ks[(idx >> 3) * 68 + (idx & 7) * 8] = kreg[it];
            *(short8*)&Vs[(idx >> 3) * 68 + (idx & 7) * 8] = vreg[it];
        }
        __syncthreads();
        // prefetch next tile AFTER the barrier (in flight through compute)
        if (kt < kt_last) {
            int s0 = (kt + 1) << 6;
#pragma unroll
            for (int it = 0; it < 2; ++it) {
                int idx = it * 256 + tid;
                kreg[it] = *(const short8*)(Kp + s0 * 64 + idx * 8);
                vreg[it] = *(const short8*)(Vp + (idx >> 3) * 2048 + s0 + (idx & 7) * 8);
            }
        }
        bool diag = (kt >= 2 * qb);    // last two 64-kp tiles overlap the diagonal

        // ---- QK both strips per kf read; strip0 P -> LDS, strip1 P -> regs
        unsigned pd[4][2];
        float lp0 = 0.f, lp1 = 0.f;
#pragma unroll
        for (int nt = 0; nt < 4; ++nt) {
            short8 kf0 = *(const short8*)&Ks[(nt * 16 + c) * 68 + g * 8];
            short8 kf1 = *(const short8*)&Ks[(nt * 16 + c) * 68 + 32 + g * 8];
            floatx4 z0 = {0.f, 0.f, 0.f, 0.f};
            z0 = __builtin_amdgcn_mfma_f32_16x16x32_bf16(kf0, qf[0][0], z0, 0, 0, 0);
            z0 = __builtin_amdgcn_mfma_f32_16x16x32_bf16(kf1, qf[0][1], z0, 0, 0, 0);
            floatx4 z1 = {0.f, 0.f, 0.f, 0.f};
            z1 = __builtin_amdgcn_mfma_f32_16x16x32_bf16(kf0, qf[1][0], z1, 0, 0, 0);
            z1 = __builtin_amdgcn_mfma_f32_16x16x32_bf16(kf1, qf[1][1], z1, 0, 0, 0);

            int kpb = kt0 + nt * 16 + g * 4;
            float p0[4], p1[4];
#pragma unroll
            for (int r = 0; r < 4; ++r) {
                float s0v = z0[r], s1v = z1[r];
                if (diag) {
                    int kp = kpb + r;
                    s0v = (kp > qg0)      ? -1e30f : s0v;
                    s1v = (kp > qg0 + 16) ? -1e30f : s1v;
                }
                p0[r] = exp2f(s0v); lp0 += p0[r];
                p1[r] = exp2f(s1v); lp1 += p1[r];
            }
            union { unsigned long long u; __hip_bfloat162 h[2]; unsigned w[2]; } pk;
            pk.h[0] = __float22bfloat162_rn(make_float2(p0[0], p0[1]));
            pk.h[1] = __float22bfloat162_rn(make_float2(p0[2], p0[3]));
            *(unsigned long long*)&Ps[wave][c * 68 + nt * 16 + g * 4] = pk.u;
            pk.h[0] = __float22bfloat162_rn(make_float2(p1[0], p1[1]));
            pk.h[1] = __float22bfloat162_rn(make_float2(p1[2], p1[3]));
            pd[nt][0] = pk.w[0]; pd[nt][1] = pk.w[1];
        }
        l_part[0] += lp0;
        l_part[1] += lp1;

        // ---- PV strip 0 (P from LDS)
#pragma unroll
        for (int ks = 0; ks < 2; ++ks) {
            short8 pf = *(const short8*)&Ps[wave][c * 68 + ks * 32 + g * 8];
#pragma unroll
            for (int nt = 0; nt < 4; ++nt) {
                short8 vf = *(const short8*)&Vs[(nt * 16 + c) * 68 + ks * 32 + g * 8];
                o_acc[0][nt] = __builtin_amdgcn_mfma_f32_16x16x32_bf16(pf, vf, o_acc[0][nt], 0, 0, 0);
            }
        }
        // ---- strip-1 P regs -> LDS (per-wave slot; lgkm-ordered within wave)
#pragma unroll
        for (int nt = 0; nt < 4; ++nt) {
            union { unsigned long long u; unsigned w[2]; } pk;
            pk.w[0] = pd[nt][0]; pk.w[1] = pd[nt][1];
            *(unsigned long long*)&Ps[wave][c * 68 + nt * 16 + g * 4] = pk.u;
        }
        // ---- PV strip 1
#pragma unroll
        for (int ks = 0; ks < 2; ++ks) {
            short8 pf = *(const short8*)&Ps[wave][c * 68 + ks * 32 + g * 8];
#pragma unroll
            for (int nt = 0; nt < 4; ++nt) {
                short8 vf = *(const short8*)&Vs[(nt * 16 + c) * 68 + ks * 32 + g * 8];
                o_acc[1][nt] = __builtin_amdgcn_mfma_f32_16x16x32_bf16(pf, vf, o_acc[1][nt], 0, 0, 0);
            }
        }
    }

    // epilogue: reduce l across g-groups, broadcast, O/l -> a[b][s][h*64+d]
#pragma unroll
    for (int ss = 0; ss < 2; ++ss) {
        float l = l_part[ss];
        l += __shfl_xor(l, 16);
        l += __shfl_xor(l, 32);
        float linv = 1.0f / l;
        float inv[4];
#pragma unroll
        for (int r = 0; r < 4; ++r)
            inv[r] = __shfl(linv, g * 4 + r);
#pragma unroll
        for (int nt = 0; nt < 4; ++nt)
#pragma unroll
            for (int r = 0; r < 4; ++r) {
                int q = q0 + (wave * 2 + ss) * 16 + g * 4 + r;
                aout[(size_t)(b * 2048 + q) * 1024 + h * 64 + nt * 16 + c] =
                    f2bf(o_acc[ss][nt][r] * inv[r]);
            }
    }
}

// ---------------- proj GEMM: [8192,1024]@[1024,1024]^T + bias -> fp32 ----------------
__global__ __launch_bounds__(256) void gemm_proj_kernel(const ushort_t* __restrict__ A,
                                                        const ushort_t* __restrict__ Bt,
                                                        const float* __restrict__ bias,
                                                        float* __restrict__ Cout) {
    const int K = 1024, N = 1024, nbn = 8;
    __shared__ __align__(16) ushort_t As[128 * 32];
    __shared__ __align__(16) ushort_t Bs[128 * 32];
    int bm = blockIdx.x / nbn, bn = blockIdx.x % nbn;
    int m0 = bm << 7, n0 = bn << 7;
    int tid = threadIdx.x;
    int wave = tid >> 6, lane = tid & 63;
    int c = lane & 15, g = lane >> 4;
    int m_off = (wave & 1) << 6, n_off = (wave >> 1) << 6;
    int ldrow = lane >> 2;
    int ldk   = (lane & 3) << 3;

    floatx4 acc[4][4];
#pragma unroll
    for (int mi = 0; mi < 4; ++mi)
#pragma unroll
        for (int ni = 0; ni < 4; ++ni) {
            floatx4 z = {0.f, 0.f, 0.f, 0.f};
            acc[mi][ni] = z;
        }

    for (int kk = 0; kk < K; kk += 32) {
        __syncthreads();
#pragma unroll
        for (int j = 0; j < 2; ++j) {
            int chunk = wave * 2 + j;
            async_ld16(A  + (size_t)(m0 + chunk * 16 + ldrow) * K + kk + ldk, &As[chunk * 512]);
            async_ld16(Bt + (size_t)(n0 + chunk * 16 + ldrow) * K + kk + ldk, &Bs[chunk * 512]);
        }
        __syncthreads();
        short8 bf[4];
#pragma unroll
        for (int ni = 0; ni < 4; ++ni)
            bf[ni] = *(const short8*)&Bs[(n_off + ni * 16 + c) * 32 + g * 8];
#pragma unroll
        for (int mi = 0; mi < 4; ++mi) {
            short8 af = *(const short8*)&As[(m_off + mi * 16 + c) * 32 + g * 8];
#pragma unroll
            for (int ni = 0; ni < 4; ++ni)
                acc[mi][ni] = __builtin_amdgcn_mfma_f32_16x16x32_bf16(af, bf[ni], acc[mi][ni], 0, 0, 0);
        }
    }

    float bv[4];
#pragma unroll
    for (int ni = 0; ni < 4; ++ni) bv[ni] = bias[n0 + n_off + ni * 16 + c];
#pragma unroll
    for (int mi = 0; mi < 4; ++mi)
#pragma unroll
        for (int ni = 0; ni < 4; ++ni)
#pragma unroll
            for (int r = 0; r < 4; ++r) {
                int row = m0 + m_off + mi * 16 + g * 4 + r;
                int col = n0 + n_off + ni * 16 + c;
                Cout[(size_t)row * N + col] = acc[mi][ni][r] + bv[ni];
            }
}

extern "C" void kernel_launch(void* const* d_in, const int* in_sizes, int n_in,
                              void* d_out, int out_size, void* d_ws, size_t ws_size,
                              hipStream_t stream) {
    const float* x        = (const float*)d_in[0];
    const float* c_attn_w = (const float*)d_in[1];
    const float* c_attn_b = (const float*)d_in[2];
    const float* c_proj_w = (const float*)d_in[3];
    const float* c_proj_b = (const float*)d_in[4];
    float* out = (float*)d_out;

    char* ws = (char*)d_ws;
    ushort_t* xb     = (ushort_t*)(ws);              // 16 MB; reused as attn output 'a'
    ushort_t* wqkvT  = (ushort_t*)(ws + 16777216);   // 6 MB
    ushort_t* wprojT = (ushort_t*)(ws + 23068672);   // 2 MB
    ushort_t* qbuf   = (ushort_t*)(ws + 25165824);   // 16 MB  [bh][s][64]  (pre-scaled)
    ushort_t* kbuf   = (ushort_t*)(ws + 41943040);   // 16 MB  [bh][s][64]
    ushort_t* vtbuf  = (ushort_t*)(ws + 58720256);   // 16 MB  [bh][64][2048]

    prep_kernel<<<12288, 256, 0, stream>>>(x, c_attn_w, c_proj_w, xb, wqkvT, wprojT);
    gemm_qkv_kernel<<<64 * 24, 256, 0, stream>>>(xb, wqkvT, c_attn_b, qbuf, kbuf, vtbuf);
    attn_kernel<<<1024, 256, 0, stream>>>(qbuf, kbuf, vtbuf, xb);
    gemm_proj_kernel<<<64 * 8, 256, 0, stream>>>(xb, wprojT, c_proj_b, out);
}

// Round 8
// 270.104 us; speedup vs baseline: 1.4349x; 1.1413x over previous
//
#include <hip/hip_runtime.h>
#include <hip/hip_bf16.h>

typedef unsigned short ushort_t;
typedef __attribute__((ext_vector_type(8))) short short8;
typedef __attribute__((ext_vector_type(4))) float floatx4;

#define LOG2E 1.4426950408889634f

__device__ __forceinline__ unsigned short f2bf(float f) {
    unsigned u = __float_as_uint(f);
    u += 0x7FFF + ((u >> 16) & 1);   // RNE
    return (unsigned short)(u >> 16);
}

__device__ __forceinline__ void async_ld16(const void* gptr, void* lptr) {
    typedef const __attribute__((address_space(1))) unsigned int TG;
    typedef __attribute__((address_space(3))) unsigned int TL;
    __builtin_amdgcn_global_load_lds((TG*)(unsigned long long)gptr,
                                     (TL*)(unsigned)(unsigned long long)lptr,
                                     16, 0, 0);
}

// ---------------- fused prep: x->bf16 | w_qkv transpose | w_proj transpose ----------------
__global__ __launch_bounds__(256) void prep_kernel(const float* __restrict__ x,
                                                   const float* __restrict__ wqkv,
                                                   const float* __restrict__ wproj,
                                                   ushort_t* __restrict__ xb,
                                                   ushort_t* __restrict__ wqkvT,
                                                   ushort_t* __restrict__ wprojT) {
    __shared__ float t[32][33];
    int bx = blockIdx.x;
    if (bx < 8192) {
        int i = bx * 256 + threadIdx.x;
        float4 v = ((const float4*)x)[i];
        unsigned long long r = (unsigned long long)f2bf(v.x)
                             | ((unsigned long long)f2bf(v.y) << 16)
                             | ((unsigned long long)f2bf(v.z) << 32)
                             | ((unsigned long long)f2bf(v.w) << 48);
        ((unsigned long long*)xb)[i] = r;
        return;
    }
    const float* in; ushort_t* out; int R, C, bidx;
    if (bx < 8192 + 3072) { in = wqkv; out = wqkvT; R = 1024; C = 3072; bidx = bx - 8192; }
    else                  { in = wproj; out = wprojT; R = 1024; C = 1024; bidx = bx - 11264; }
    int nbc = C >> 5;
    int bc = bidx % nbc, br = bidx / nbc;
    int tx = threadIdx.x & 31, ty = threadIdx.x >> 5;   // 32 x 8
    int r0 = br << 5, c0 = bc << 5;
#pragma unroll
    for (int j = 0; j < 4; ++j)
        t[ty + j * 8][tx] = in[(size_t)(r0 + ty + j * 8) * C + c0 + tx];
    __syncthreads();
#pragma unroll
    for (int j = 0; j < 4; ++j)
        out[(size_t)(c0 + ty + j * 8) * R + r0 + tx] = f2bf(t[tx][ty + j * 8]);
}

// ---------------- QKV GEMM: [8192,1024]@[1024,3072]^T + bias -> split Q/K/Vt ----------------
// Q,K: [bh][s][64] bf16 ; Vt: [bh][64][2048] bf16
// Q (incl. bias) is pre-scaled by 0.125*log2(e) so attn can use exp2 directly.
__global__ __launch_bounds__(256) void gemm_qkv_kernel(const ushort_t* __restrict__ A,
                                                       const ushort_t* __restrict__ Bt,
                                                       const float* __restrict__ bias,
                                                       ushort_t* __restrict__ qbuf,
                                                       ushort_t* __restrict__ kbuf,
                                                       ushort_t* __restrict__ vtbuf) {
    const int K = 1024, nbn = 24;
    __shared__ __align__(16) ushort_t As[128 * 32];
    __shared__ __align__(16) ushort_t Bs[128 * 32];
    int bm = blockIdx.x / nbn, bn = blockIdx.x % nbn;
    int m0 = bm << 7, n0 = bn << 7;
    int tid = threadIdx.x;
    int wave = tid >> 6, lane = tid & 63;
    int c = lane & 15, g = lane >> 4;
    int m_off = (wave & 1) << 6, n_off = (wave >> 1) << 6;
    int ldrow = lane >> 2;
    int ldk   = (lane & 3) << 3;

    floatx4 acc[4][4];
#pragma unroll
    for (int mi = 0; mi < 4; ++mi)
#pragma unroll
        for (int ni = 0; ni < 4; ++ni) {
            floatx4 z = {0.f, 0.f, 0.f, 0.f};
            acc[mi][ni] = z;
        }

    for (int kk = 0; kk < K; kk += 32) {
        __syncthreads();
#pragma unroll
        for (int j = 0; j < 2; ++j) {
            int chunk = wave * 2 + j;
            async_ld16(A  + (size_t)(m0 + chunk * 16 + ldrow) * K + kk + ldk, &As[chunk * 512]);
            async_ld16(Bt + (size_t)(n0 + chunk * 16 + ldrow) * K + kk + ldk, &Bs[chunk * 512]);
        }
        __syncthreads();
        short8 bf[4];
#pragma unroll
        for (int ni = 0; ni < 4; ++ni)
            bf[ni] = *(const short8*)&Bs[(n_off + ni * 16 + c) * 32 + g * 8];
#pragma unroll
        for (int mi = 0; mi < 4; ++mi) {
            short8 af = *(const short8*)&As[(m_off + mi * 16 + c) * 32 + g * 8];
#pragma unroll
            for (int ni = 0; ni < 4; ++ni)
                acc[mi][ni] = __builtin_amdgcn_mfma_f32_16x16x32_bf16(af, bf[ni], acc[mi][ni], 0, 0, 0);
        }
    }

    int sec = n0 >> 10;               // 0=Q 1=K 2=V (block-uniform; 1024%128==0)
    float scl = (sec == 0) ? (0.125f * LOG2E) : 1.0f;
    float bv[4]; int hh[4], dd[4];
#pragma unroll
    for (int ni = 0; ni < 4; ++ni) {
        int coln = n0 + n_off + ni * 16 + c;
        bv[ni] = bias[coln];
        int coll = coln & 1023;
        hh[ni] = coll >> 6; dd[ni] = coll & 63;
    }
#pragma unroll
    for (int mi = 0; mi < 4; ++mi) {
        int rowb = m0 + m_off + mi * 16 + g * 4;     // +r
        int bb = rowb >> 11, sbase = rowb & 2047;
#pragma unroll
        for (int ni = 0; ni < 4; ++ni) {
            size_t bhn = (size_t)(bb * 16 + hh[ni]);
            if (sec == 2) {
                unsigned long long pk = 0;
#pragma unroll
                for (int r = 0; r < 4; ++r)
                    pk |= (unsigned long long)f2bf(acc[mi][ni][r] + bv[ni]) << (16 * r);
                *(unsigned long long*)(vtbuf + bhn * 131072 + (size_t)dd[ni] * 2048 + sbase) = pk;
            } else {
                ushort_t* dst = (sec == 0 ? qbuf : kbuf) + (bhn * 2048 + sbase) * 64 + dd[ni];
#pragma unroll
                for (int r = 0; r < 4; ++r)
                    dst[r * 64] = f2bf((acc[mi][ni][r] + bv[ni]) * scl);
            }
        }
    }
}

// ---------------- flash attention: 1 block = (b,h) x 64 q-rows, 64-kp tiles ----------------
// Single strip per wave (R7's two-strip design spilled at any occupancy >3:
// arch-VGPR demand ~80 vs 64 budget). Demand now ~85 total -> fits (256,5)'s
// 102-reg budget spill-free; 26.1 KB LDS -> 5 blocks/CU. Conflict-free
// stride-68 LDS, transposed softmax, no online max, LPT dispatch,
// post-barrier register prefetch.
__global__ __launch_bounds__(256, 5) void attn_kernel(const ushort_t* __restrict__ qb_,
                                                      const ushort_t* __restrict__ kb_,
                                                      const ushort_t* __restrict__ vtb_,
                                                      ushort_t* __restrict__ aout) {
    __shared__ __align__(16) ushort_t Ks[64 * 68];       // [kp][d] stride 68
    __shared__ __align__(16) ushort_t Vs[64 * 68];       // [d][kp] stride 68
    __shared__ __align__(16) ushort_t Ps[4][16 * 68];    // per-wave P[q][kp]
    int bx = blockIdx.x;
    int qb = 31 - (bx >> 6);          // LPT: longest blocks dispatch first
    int bhix = bx & 63;
    int b = bhix >> 4, h = bhix & 15;
    int q0 = qb << 6;
    int tid = threadIdx.x, wave = tid >> 6, lane = tid & 63;
    int c = lane & 15, g = lane >> 4;
    size_t bh = (size_t)(b * 16 + h);

    const ushort_t* Qp = qb_ + (bh * 2048 + q0) * 64;
    const ushort_t* Kp = kb_ + bh * 131072;
    const ushort_t* Vp = vtb_ + bh * 131072;

    // Q fragment for this wave's 16 q-rows (B-operand of K·Q^T)
    int qr = wave * 16 + c;
    short8 qf0 = *(const short8*)(Qp + qr * 64 + g * 8);
    short8 qf1 = *(const short8*)(Qp + qr * 64 + 32 + g * 8);

    float l_part = 0.f;
    floatx4 o_acc[4];
#pragma unroll
    for (int nt = 0; nt < 4; ++nt) { floatx4 z = {0.f,0.f,0.f,0.f}; o_acc[nt] = z; }

    // prefetch tile 0 into regs (64 kp x 64 d = 8 KB each for K and V)
    short8 kreg[2], vreg[2];
#pragma unroll
    for (int it = 0; it < 2; ++it) {
        int idx = it * 256 + tid;
        kreg[it] = *(const short8*)(Kp + idx * 8);
        vreg[it] = *(const short8*)(Vp + (idx >> 3) * 2048 + (idx & 7) * 8);
    }

    int qg = q0 + wave * 16 + c;       // this lane's q row
    for (int kt = 0; kt <= qb; ++kt) {
        int kt0 = kt << 6;
        __syncthreads();
#pragma unroll
        for (int it = 0; it < 2; ++it) {
            int idx = it * 256 + tid;
            *(short8*)&Ks[(idx >> 3) * 68 + (idx & 7) * 8] = kreg[it];
            *(short8*)&Vs[(idx >> 3) * 68 + (idx & 7) * 8] = vreg[it];
        }
        __syncthreads();
        // prefetch next tile AFTER the barrier (in flight through compute)
        if (kt < qb) {
            int s0 = (kt + 1) << 6;
#pragma unroll
            for (int it = 0; it < 2; ++it) {
                int idx = it * 256 + tid;
                kreg[it] = *(const short8*)(Kp + s0 * 64 + idx * 8);
                vreg[it] = *(const short8*)(Vp + (idx >> 3) * 2048 + s0 + (idx & 7) * 8);
            }
        }
        bool diag = (kt == qb);        // only the last tile crosses the diagonal

        // ---- S^T = K·Q^T ; mask+exp2 per nt; P -> per-wave LDS strip
        float lp = 0.f;
#pragma unroll
        for (int nt = 0; nt < 4; ++nt) {
            short8 kf0 = *(const short8*)&Ks[(nt * 16 + c) * 68 + g * 8];
            short8 kf1 = *(const short8*)&Ks[(nt * 16 + c) * 68 + 32 + g * 8];
            floatx4 z = {0.f, 0.f, 0.f, 0.f};
            z = __builtin_amdgcn_mfma_f32_16x16x32_bf16(kf0, qf0, z, 0, 0, 0);
            z = __builtin_amdgcn_mfma_f32_16x16x32_bf16(kf1, qf1, z, 0, 0, 0);

            int kpb = kt0 + nt * 16 + g * 4;
            float p[4];
#pragma unroll
            for (int r = 0; r < 4; ++r) {
                float s = z[r];
                if (diag) s = (kpb + r > qg) ? -1e30f : s;
                p[r] = exp2f(s);       // Q pre-scaled by 0.125*log2e
                lp += p[r];
            }
            union { unsigned long long u; __hip_bfloat162 h2[2]; } pk;
            pk.h2[0] = __float22bfloat162_rn(make_float2(p[0], p[1]));
            pk.h2[1] = __float22bfloat162_rn(make_float2(p[2], p[3]));
            *(unsigned long long*)&Ps[wave][c * 68 + nt * 16 + g * 4] = pk.u;
        }
        l_part += lp;

        // ---- O += P @ V
#pragma unroll
        for (int ks = 0; ks < 2; ++ks) {
            short8 pf = *(const short8*)&Ps[wave][c * 68 + ks * 32 + g * 8];
#pragma unroll
            for (int nt = 0; nt < 4; ++nt) {
                short8 vf = *(const short8*)&Vs[(nt * 16 + c) * 68 + ks * 32 + g * 8];
                o_acc[nt] = __builtin_amdgcn_mfma_f32_16x16x32_bf16(pf, vf, o_acc[nt], 0, 0, 0);
            }
        }
    }

    // epilogue: reduce l across g-groups, broadcast, O/l -> a[b][s][h*64+d]
    float l = l_part;
    l += __shfl_xor(l, 16);
    l += __shfl_xor(l, 32);
    float linv = 1.0f / l;             // lanes {c,c+16,..} hold l for q=wave*16+c
    float inv[4];
#pragma unroll
    for (int r = 0; r < 4; ++r)
        inv[r] = __shfl(linv, g * 4 + r);
#pragma unroll
    for (int nt = 0; nt < 4; ++nt)
#pragma unroll
        for (int r = 0; r < 4; ++r) {
            int q = q0 + wave * 16 + g * 4 + r;
            aout[(size_t)(b * 2048 + q) * 1024 + h * 64 + nt * 16 + c] =
                f2bf(o_acc[nt][r] * inv[r]);
        }
}

// ---------------- proj GEMM: [8192,1024]@[1024,1024]^T + bias -> fp32 ----------------
__global__ __launch_bounds__(256) void gemm_proj_kernel(const ushort_t* __restrict__ A,
                                                        const ushort_t* __restrict__ Bt,
                                                        const float* __restrict__ bias,
                                                        float* __restrict__ Cout) {
    const int K = 1024, N = 1024, nbn = 8;
    __shared__ __align__(16) ushort_t As[128 * 32];
    __shared__ __align__(16) ushort_t Bs[128 * 32];
    int bm = blockIdx.x / nbn, bn = blockIdx.x % nbn;
    int m0 = bm << 7, n0 = bn << 7;
    int tid = threadIdx.x;
    int wave = tid >> 6, lane = tid & 63;
    int c = lane & 15, g = lane >> 4;
    int m_off = (wave & 1) << 6, n_off = (wave >> 1) << 6;
    int ldrow = lane >> 2;
    int ldk   = (lane & 3) << 3;

    floatx4 acc[4][4];
#pragma unroll
    for (int mi = 0; mi < 4; ++mi)
#pragma unroll
        for (int ni = 0; ni < 4; ++ni) {
            floatx4 z = {0.f, 0.f, 0.f, 0.f};
            acc[mi][ni] = z;
        }

    for (int kk = 0; kk < K; kk += 32) {
        __syncthreads();
#pragma unroll
        for (int j = 0; j < 2; ++j) {
            int chunk = wave * 2 + j;
            async_ld16(A  + (size_t)(m0 + chunk * 16 + ldrow) * K + kk + ldk, &As[chunk * 512]);
            async_ld16(Bt + (size_t)(n0 + chunk * 16 + ldrow) * K + kk + ldk, &Bs[chunk * 512]);
        }
        __syncthreads();
        short8 bf[4];
#pragma unroll
        for (int ni = 0; ni < 4; ++ni)
            bf[ni] = *(const short8*)&Bs[(n_off + ni * 16 + c) * 32 + g * 8];
#pragma unroll
        for (int mi = 0; mi < 4; ++mi) {
            short8 af = *(const short8*)&As[(m_off + mi * 16 + c) * 32 + g * 8];
#pragma unroll
            for (int ni = 0; ni < 4; ++ni)
                acc[mi][ni] = __builtin_amdgcn_mfma_f32_16x16x32_bf16(af, bf[ni], acc[mi][ni], 0, 0, 0);
        }
    }

    float bv[4];
#pragma unroll
    for (int ni = 0; ni < 4; ++ni) bv[ni] = bias[n0 + n_off + ni * 16 + c];
#pragma unroll
    for (int mi = 0; mi < 4; ++mi)
#pragma unroll
        for (int ni = 0; ni < 4; ++ni)
#pragma unroll
            for (int r = 0; r < 4; ++r) {
                int row = m0 + m_off + mi * 16 + g * 4 + r;
                int col = n0 + n_off + ni * 16 + c;
                Cout[(size_t)row * N + col] = acc[mi][ni][r] + bv[ni];
            }
}

extern "C" void kernel_launch(void* const* d_in, const int* in_sizes, int n_in,
                              void* d_out, int out_size, void* d_ws, size_t ws_size,
                              hipStream_t stream) {
    const float* x        = (const float*)d_in[0];
    const float* c_attn_w = (const float*)d_in[1];
    const float* c_attn_b = (const float*)d_in[2];
    const float* c_proj_w = (const float*)d_in[3];
    const float* c_proj_b = (const float*)d_in[4];
    float* out = (float*)d_out;

    char* ws = (char*)d_ws;
    ushort_t* xb     = (ushort_t*)(ws);              // 16 MB; reused as attn output 'a'
    ushort_t* wqkvT  = (ushort_t*)(ws + 16777216);   // 6 MB
    ushort_t* wprojT = (ushort_t*)(ws + 23068672);   // 2 MB
    ushort_t* qbuf   = (ushort_t*)(ws + 25165824);   // 16 MB  [bh][s][64]  (pre-scaled)
    ushort_t* kbuf   = (ushort_t*)(ws + 41943040);   // 16 MB  [bh][s][64]
    ushort_t* vtbuf  = (ushort_t*)(ws + 58720256);   // 16 MB  [bh][64][2048]

    prep_kernel<<<12288, 256, 0, stream>>>(x, c_attn_w, c_proj_w, xb, wqkvT, wprojT);
    gemm_qkv_kernel<<<64 * 24, 256, 0, stream>>>(xb, wqkvT, c_attn_b, qbuf, kbuf, vtbuf);
    attn_kernel<<<2048, 256, 0, stream>>>(qbuf, kbuf, vtbuf, xb);
    gemm_proj_kernel<<<64 * 8, 256, 0, stream>>>(xb, wprojT, c_proj_b, out);
}

// Round 9
// 268.577 us; speedup vs baseline: 1.4431x; 1.0057x over previous
//
#include <hip/hip_runtime.h>
#include <hip/hip_bf16.h>

typedef unsigned short ushort_t;
typedef __attribute__((ext_vector_type(8))) short short8;
typedef __attribute__((ext_vector_type(4))) float floatx4;

#define LOG2E 1.4426950408889634f

__device__ __forceinline__ unsigned short f2bf(float f) {
    unsigned u = __float_as_uint(f);
    u += 0x7FFF + ((u >> 16) & 1);   // RNE
    return (unsigned short)(u >> 16);
}

__device__ __forceinline__ void async_ld16(const void* gptr, void* lptr) {
    typedef const __attribute__((address_space(1))) unsigned int TG;
    typedef __attribute__((address_space(3))) unsigned int TL;
    __builtin_amdgcn_global_load_lds((TG*)(unsigned long long)gptr,
                                     (TL*)(unsigned)(unsigned long long)lptr,
                                     16, 0, 0);
}

// ---------------- fused prep: x->bf16 | w_qkv transpose | w_proj transpose ----------------
__global__ __launch_bounds__(256) void prep_kernel(const float* __restrict__ x,
                                                   const float* __restrict__ wqkv,
                                                   const float* __restrict__ wproj,
                                                   ushort_t* __restrict__ xb,
                                                   ushort_t* __restrict__ wqkvT,
                                                   ushort_t* __restrict__ wprojT) {
    __shared__ float t[32][33];
    int bx = blockIdx.x;
    if (bx < 8192) {
        int i = bx * 256 + threadIdx.x;
        float4 v = ((const float4*)x)[i];
        unsigned long long r = (unsigned long long)f2bf(v.x)
                             | ((unsigned long long)f2bf(v.y) << 16)
                             | ((unsigned long long)f2bf(v.z) << 32)
                             | ((unsigned long long)f2bf(v.w) << 48);
        ((unsigned long long*)xb)[i] = r;
        return;
    }
    const float* in; ushort_t* out; int R, C, bidx;
    if (bx < 8192 + 3072) { in = wqkv; out = wqkvT; R = 1024; C = 3072; bidx = bx - 8192; }
    else                  { in = wproj; out = wprojT; R = 1024; C = 1024; bidx = bx - 11264; }
    int nbc = C >> 5;
    int bc = bidx % nbc, br = bidx / nbc;
    int tx = threadIdx.x & 31, ty = threadIdx.x >> 5;   // 32 x 8
    int r0 = br << 5, c0 = bc << 5;
#pragma unroll
    for (int j = 0; j < 4; ++j)
        t[ty + j * 8][tx] = in[(size_t)(r0 + ty + j * 8) * C + c0 + tx];
    __syncthreads();
#pragma unroll
    for (int j = 0; j < 4; ++j)
        out[(size_t)(c0 + ty + j * 8) * R + r0 + tx] = f2bf(t[tx][ty + j * 8]);
}

// ---------------- QKV GEMM: [8192,1024]@[1024,3072]^T + bias -> split Q/K/Vt ----------------
// Q,K: [bh][s][64] bf16 ; Vt: [bh][64][2048] bf16
// Q (incl. bias) pre-scaled by 0.125*log2(e).
// Epilogue restages the C-tile through LDS (smem reused after the K-loop) so
// all global writes are coalesced b128 into contiguous per-head regions —
// replaces R8's 64 scalar stride-64 u16 stores per lane.
__global__ __launch_bounds__(256) void gemm_qkv_kernel(const ushort_t* __restrict__ A,
                                                       const ushort_t* __restrict__ Bt,
                                                       const float* __restrict__ bias,
                                                       ushort_t* __restrict__ qbuf,
                                                       ushort_t* __restrict__ kbuf,
                                                       ushort_t* __restrict__ vtbuf) {
    const int K = 1024, nbn = 24;
    __shared__ __align__(16) ushort_t smem[18432];   // 36.9 KB; K-loop uses first 16 KB
    ushort_t* As = smem;          // 4096
    ushort_t* Bs = smem + 4096;   // 4096
    int bm = blockIdx.x / nbn, bn = blockIdx.x % nbn;
    int m0 = bm << 7, n0 = bn << 7;
    int tid = threadIdx.x;
    int wave = tid >> 6, lane = tid & 63;
    int c = lane & 15, g = lane >> 4;
    int m_off = (wave & 1) << 6, n_off = (wave >> 1) << 6;
    int ldrow = lane >> 2;
    int ldk   = (lane & 3) << 3;

    floatx4 acc[4][4];
#pragma unroll
    for (int mi = 0; mi < 4; ++mi)
#pragma unroll
        for (int ni = 0; ni < 4; ++ni) {
            floatx4 z = {0.f, 0.f, 0.f, 0.f};
            acc[mi][ni] = z;
        }

    for (int kk = 0; kk < K; kk += 32) {
        __syncthreads();
#pragma unroll
        for (int j = 0; j < 2; ++j) {
            int chunk = wave * 2 + j;
            async_ld16(A  + (size_t)(m0 + chunk * 16 + ldrow) * K + kk + ldk, &As[chunk * 512]);
            async_ld16(Bt + (size_t)(n0 + chunk * 16 + ldrow) * K + kk + ldk, &Bs[chunk * 512]);
        }
        __syncthreads();
        short8 bf[4];
#pragma unroll
        for (int ni = 0; ni < 4; ++ni)
            bf[ni] = *(const short8*)&Bs[(n_off + ni * 16 + c) * 32 + g * 8];
#pragma unroll
        for (int mi = 0; mi < 4; ++mi) {
            short8 af = *(const short8*)&As[(m_off + mi * 16 + c) * 32 + g * 8];
#pragma unroll
            for (int ni = 0; ni < 4; ++ni)
                acc[mi][ni] = __builtin_amdgcn_mfma_f32_16x16x32_bf16(af, bf[ni], acc[mi][ni], 0, 0, 0);
        }
    }

    int sec = n0 >> 10;               // 0=Q 1=K 2=V (block-uniform)
    int h0 = (n0 & 1023) >> 6;        // first head in this 128-col tile
    int b  = m0 >> 11, sbase = m0 & 2047;
    int bh0 = b * 16 + h0;
    float bv[4];
#pragma unroll
    for (int ni = 0; ni < 4; ++ni) bv[ni] = bias[n0 + n_off + ni * 16 + c];

    __syncthreads();                  // all waves done reading As/Bs -> reuse smem
    int hl = wave >> 1;               // head-local: waves {0,1}->h0, {2,3}->h0+1

    if (sec < 2) {
        // stage [hl][row 128][col 64], row stride 72 (16B-aligned rows)
        float scl = (sec == 0) ? (0.125f * LOG2E) : 1.0f;
#pragma unroll
        for (int mi = 0; mi < 4; ++mi)
#pragma unroll
            for (int ni = 0; ni < 4; ++ni) {
                int colb = ni * 16 + c;
#pragma unroll
                for (int r = 0; r < 4; ++r) {
                    int row = m_off + mi * 16 + g * 4 + r;
                    smem[hl * 9216 + row * 72 + colb] = f2bf((acc[mi][ni][r] + bv[ni]) * scl);
                }
            }
        __syncthreads();
        // copy: thread t -> one q-row (64 cols = 128 B contiguous)
        ushort_t* dstbase = (sec == 0 ? qbuf : kbuf);
        int hl2 = tid >> 7, row = tid & 127;
        const ushort_t* src = &smem[hl2 * 9216 + row * 72];
        ushort_t* dst = dstbase + (size_t)(bh0 + hl2) * 131072 + (size_t)(sbase + row) * 64;
#pragma unroll
        for (int j = 0; j < 8; ++j)
            *(short8*)(dst + j * 8) = *(const short8*)(src + j * 8);
    } else {
        // stage [hl][d 64][s 128], d stride 136; packed b64 along s (r-consecutive)
#pragma unroll
        for (int mi = 0; mi < 4; ++mi)
#pragma unroll
            for (int ni = 0; ni < 4; ++ni) {
                int d = ni * 16 + c;
                int rowb = m_off + mi * 16 + g * 4;
                unsigned long long pk = 0;
#pragma unroll
                for (int r = 0; r < 4; ++r)
                    pk |= (unsigned long long)f2bf(acc[mi][ni][r] + bv[ni]) << (16 * r);
                *(unsigned long long*)&smem[hl * 8704 + d * 136 + rowb] = pk;
            }
        __syncthreads();
        // copy: thread pair -> one d-row half (64 s = 128 B contiguous)
        int rr = tid >> 1, half = tid & 1;
        int hl2 = rr >> 6, d = rr & 63;
        const ushort_t* src = &smem[hl2 * 8704 + d * 136 + half * 64];
        ushort_t* dst = vtbuf + (size_t)(bh0 + hl2) * 131072 + (size_t)d * 2048 + sbase + half * 64;
#pragma unroll
        for (int j = 0; j < 8; ++j)
            *(short8*)(dst + j * 8) = *(const short8*)(src + j * 8);
    }
}

// ---------------- flash attention: 1 block = (b,h) x 64 q-rows, 64-kp tiles ----------------
// Single strip per wave; 26.1 KB LDS; (256,5) -> 5 blocks/CU spill-free.
// Conflict-free stride-68 LDS, transposed softmax, no online max, LPT
// dispatch, post-barrier register prefetch.
__global__ __launch_bounds__(256, 5) void attn_kernel(const ushort_t* __restrict__ qb_,
                                                      const ushort_t* __restrict__ kb_,
                                                      const ushort_t* __restrict__ vtb_,
                                                      ushort_t* __restrict__ aout) {
    __shared__ __align__(16) ushort_t Ks[64 * 68];       // [kp][d] stride 68
    __shared__ __align__(16) ushort_t Vs[64 * 68];       // [d][kp] stride 68
    __shared__ __align__(16) ushort_t Ps[4][16 * 68];    // per-wave P[q][kp]
    int bx = blockIdx.x;
    int qb = 31 - (bx >> 6);          // LPT: longest blocks dispatch first
    int bhix = bx & 63;
    int b = bhix >> 4, h = bhix & 15;
    int q0 = qb << 6;
    int tid = threadIdx.x, wave = tid >> 6, lane = tid & 63;
    int c = lane & 15, g = lane >> 4;
    size_t bh = (size_t)(b * 16 + h);

    const ushort_t* Qp = qb_ + (bh * 2048 + q0) * 64;
    const ushort_t* Kp = kb_ + bh * 131072;
    const ushort_t* Vp = vtb_ + bh * 131072;

    int qr = wave * 16 + c;
    short8 qf0 = *(const short8*)(Qp + qr * 64 + g * 8);
    short8 qf1 = *(const short8*)(Qp + qr * 64 + 32 + g * 8);

    float l_part = 0.f;
    floatx4 o_acc[4];
#pragma unroll
    for (int nt = 0; nt < 4; ++nt) { floatx4 z = {0.f,0.f,0.f,0.f}; o_acc[nt] = z; }

    short8 kreg[2], vreg[2];
#pragma unroll
    for (int it = 0; it < 2; ++it) {
        int idx = it * 256 + tid;
        kreg[it] = *(const short8*)(Kp + idx * 8);
        vreg[it] = *(const short8*)(Vp + (idx >> 3) * 2048 + (idx & 7) * 8);
    }

    int qg = q0 + wave * 16 + c;
    for (int kt = 0; kt <= qb; ++kt) {
        int kt0 = kt << 6;
        __syncthreads();
#pragma unroll
        for (int it = 0; it < 2; ++it) {
            int idx = it * 256 + tid;
            *(short8*)&Ks[(idx >> 3) * 68 + (idx & 7) * 8] = kreg[it];
            *(short8*)&Vs[(idx >> 3) * 68 + (idx & 7) * 8] = vreg[it];
        }
        __syncthreads();
        if (kt < qb) {
            int s0 = (kt + 1) << 6;
#pragma unroll
            for (int it = 0; it < 2; ++it) {
                int idx = it * 256 + tid;
                kreg[it] = *(const short8*)(Kp + s0 * 64 + idx * 8);
                vreg[it] = *(const short8*)(Vp + (idx >> 3) * 2048 + s0 + (idx & 7) * 8);
            }
        }
        bool diag = (kt == qb);

        float lp = 0.f;
#pragma unroll
        for (int nt = 0; nt < 4; ++nt) {
            short8 kf0 = *(const short8*)&Ks[(nt * 16 + c) * 68 + g * 8];
            short8 kf1 = *(const short8*)&Ks[(nt * 16 + c) * 68 + 32 + g * 8];
            floatx4 z = {0.f, 0.f, 0.f, 0.f};
            z = __builtin_amdgcn_mfma_f32_16x16x32_bf16(kf0, qf0, z, 0, 0, 0);
            z = __builtin_amdgcn_mfma_f32_16x16x32_bf16(kf1, qf1, z, 0, 0, 0);

            int kpb = kt0 + nt * 16 + g * 4;
            float p[4];
#pragma unroll
            for (int r = 0; r < 4; ++r) {
                float s = z[r];
                if (diag) s = (kpb + r > qg) ? -1e30f : s;
                p[r] = exp2f(s);
                lp += p[r];
            }
            union { unsigned long long u; __hip_bfloat162 h2[2]; } pk;
            pk.h2[0] = __float22bfloat162_rn(make_float2(p[0], p[1]));
            pk.h2[1] = __float22bfloat162_rn(make_float2(p[2], p[3]));
            *(unsigned long long*)&Ps[wave][c * 68 + nt * 16 + g * 4] = pk.u;
        }
        l_part += lp;

#pragma unroll
        for (int ks = 0; ks < 2; ++ks) {
            short8 pf = *(const short8*)&Ps[wave][c * 68 + ks * 32 + g * 8];
#pragma unroll
            for (int nt = 0; nt < 4; ++nt) {
                short8 vf = *(const short8*)&Vs[(nt * 16 + c) * 68 + ks * 32 + g * 8];
                o_acc[nt] = __builtin_amdgcn_mfma_f32_16x16x32_bf16(pf, vf, o_acc[nt], 0, 0, 0);
            }
        }
    }

    float l = l_part;
    l += __shfl_xor(l, 16);
    l += __shfl_xor(l, 32);
    float linv = 1.0f / l;
    float inv[4];
#pragma unroll
    for (int r = 0; r < 4; ++r)
        inv[r] = __shfl(linv, g * 4 + r);
#pragma unroll
    for (int nt = 0; nt < 4; ++nt)
#pragma unroll
        for (int r = 0; r < 4; ++r) {
            int q = q0 + wave * 16 + g * 4 + r;
            aout[(size_t)(b * 2048 + q) * 1024 + h * 64 + nt * 16 + c] =
                f2bf(o_acc[nt][r] * inv[r]);
        }
}

// ---------------- proj GEMM: [8192,1024]@[1024,1024]^T + bias -> fp32 ----------------
__global__ __launch_bounds__(256) void gemm_proj_kernel(const ushort_t* __restrict__ A,
                                                        const ushort_t* __restrict__ Bt,
                                                        const float* __restrict__ bias,
                                                        float* __restrict__ Cout) {
    const int K = 1024, N = 1024, nbn = 8;
    __shared__ __align__(16) ushort_t As[128 * 32];
    __shared__ __align__(16) ushort_t Bs[128 * 32];
    int bm = blockIdx.x / nbn, bn = blockIdx.x % nbn;
    int m0 = bm << 7, n0 = bn << 7;
    int tid = threadIdx.x;
    int wave = tid >> 6, lane = tid & 63;
    int c = lane & 15, g = lane >> 4;
    int m_off = (wave & 1) << 6, n_off = (wave >> 1) << 6;
    int ldrow = lane >> 2;
    int ldk   = (lane & 3) << 3;

    floatx4 acc[4][4];
#pragma unroll
    for (int mi = 0; mi < 4; ++mi)
#pragma unroll
        for (int ni = 0; ni < 4; ++ni) {
            floatx4 z = {0.f, 0.f, 0.f, 0.f};
            acc[mi][ni] = z;
        }

    for (int kk = 0; kk < K; kk += 32) {
        __syncthreads();
#pragma unroll
        for (int j = 0; j < 2; ++j) {
            int chunk = wave * 2 + j;
            async_ld16(A  + (size_t)(m0 + chunk * 16 + ldrow) * K + kk + ldk, &As[chunk * 512]);
            async_ld16(Bt + (size_t)(n0 + chunk * 16 + ldrow) * K + kk + ldk, &Bs[chunk * 512]);
        }
        __syncthreads();
        short8 bf[4];
#pragma unroll
        for (int ni = 0; ni < 4; ++ni)
            bf[ni] = *(const short8*)&Bs[(n_off + ni * 16 + c) * 32 + g * 8];
#pragma unroll
        for (int mi = 0; mi < 4; ++mi) {
            short8 af = *(const short8*)&As[(m_off + mi * 16 + c) * 32 + g * 8];
#pragma unroll
            for (int ni = 0; ni < 4; ++ni)
                acc[mi][ni] = __builtin_amdgcn_mfma_f32_16x16x32_bf16(af, bf[ni], acc[mi][ni], 0, 0, 0);
        }
    }

    float bv[4];
#pragma unroll
    for (int ni = 0; ni < 4; ++ni) bv[ni] = bias[n0 + n_off + ni * 16 + c];
#pragma unroll
    for (int mi = 0; mi < 4; ++mi)
#pragma unroll
        for (int ni = 0; ni < 4; ++ni)
#pragma unroll
            for (int r = 0; r < 4; ++r) {
                int row = m0 + m_off + mi * 16 + g * 4 + r;
                int col = n0 + n_off + ni * 16 + c;
                Cout[(size_t)row * N + col] = acc[mi][ni][r] + bv[ni];
            }
}

extern "C" void kernel_launch(void* const* d_in, const int* in_sizes, int n_in,
                              void* d_out, int out_size, void* d_ws, size_t ws_size,
                              hipStream_t stream) {
    const float* x        = (const float*)d_in[0];
    const float* c_attn_w = (const float*)d_in[1];
    const float* c_attn_b = (const float*)d_in[2];
    const float* c_proj_w = (const float*)d_in[3];
    const float* c_proj_b = (const float*)d_in[4];
    float* out = (float*)d_out;

    char* ws = (char*)d_ws;
    ushort_t* xb     = (ushort_t*)(ws);              // 16 MB; reused as attn output 'a'
    ushort_t* wqkvT  = (ushort_t*)(ws + 16777216);   // 6 MB
    ushort_t* wprojT = (ushort_t*)(ws + 23068672);   // 2 MB
    ushort_t* qbuf   = (ushort_t*)(ws + 25165824);   // 16 MB  [bh][s][64]  (pre-scaled)
    ushort_t* kbuf   = (ushort_t*)(ws + 41943040);   // 16 MB  [bh][s][64]
    ushort_t* vtbuf  = (ushort_t*)(ws + 58720256);   // 16 MB  [bh][64][2048]

    prep_kernel<<<12288, 256, 0, stream>>>(x, c_attn_w, c_proj_w, xb, wqkvT, wprojT);
    gemm_qkv_kernel<<<64 * 24, 256, 0, stream>>>(xb, wqkvT, c_attn_b, qbuf, kbuf, vtbuf);
    attn_kernel<<<2048, 256, 0, stream>>>(qbuf, kbuf, vtbuf, xb);
    gemm_proj_kernel<<<64 * 8, 256, 0, stream>>>(xb, wprojT, c_proj_b, out);
}